// Round 1
// baseline (290.595 us; speedup 1.0000x reference)
//
#include <hip/hip_runtime.h>
#include <stdint.h>

typedef __attribute__((ext_vector_type(4))) float f32x4;
typedef __attribute__((ext_vector_type(4))) _Float16 f16x4;

// ---- geometry (fixed problem) ----
// x: (16,64,128,128) fp32; weight: (64,64,6,6) fp32 (Winograd-domain); bias fp32
// out: (16,64,128,128) fp32. 4x4 output tiles, nt=32/dim, 16384 tiles, PAD=1.
#define WB_BYTES 294912              // 36*64*64 f16 relayout of weights

// ---------------- Kernel 0: weight relayout fp32(co,cin,ab) -> f16 [ab][co*64+cin] ----------------
__global__ __launch_bounds__(256) void wtrans(const float* __restrict__ wf, _Float16* __restrict__ wh) {
    int tid = blockIdx.x * 256 + threadIdx.x;    // 0..4095  == co*64+cin
    const float* src = wf + tid * 36;
    float w[36];
#pragma unroll
    for (int i = 0; i < 9; i++) {
        f32x4 v = *(const f32x4*)(src + 4 * i);
        w[4*i+0] = v[0]; w[4*i+1] = v[1]; w[4*i+2] = v[2]; w[4*i+3] = v[3];
    }
#pragma unroll
    for (int ab = 0; ab < 36; ab++) wh[ab * 4096 + tid] = (_Float16)w[ab];  // coalesced per ab
}

// ---------------- Fused kernel ----------------
// Block = 4x4 tile super-block (16 tiles) x 32 couts (ch half) x all 64 cin.
// 256 threads = 4 waves = (sh: a-rows 0-2 / 3-5) x (cog: 16-cout group).
// Per 16-cin quarter rq: stage 16x18x18 halo into X (stride 343), transform
// 256 (tile,cin) tasks -> Vs [36ab][tile16][cin16] f16, then per wave 18 MFMAs
// (16x16x16 f16, K=16) into acc[18] (72 regs -> 4 waves/SIMD fits 128 VGPR).
// Epilogue: partial AT-transform per a-half; sh=1 writes partial 4x4 y to LDS
// (lane-linear, conflict-free), sh=0 combines + bias + stores.
#define XS 343                                   // 18*18=324 padded to odd 343
__global__ __launch_bounds__(256, 4) void wino_fused(const float* __restrict__ x,
                                                     const _Float16* __restrict__ wh,
                                                     const float* __restrict__ bias,
                                                     float* __restrict__ out) {
    __shared__ __align__(16) float SM[10096];    // 40,384 B -> 4 blocks/CU
    float* X = SM;                               // [16][343] fp32 = 21,952 B
    _Float16* Vs = (_Float16*)(SM + 16 * XS);    // [36][16][16] f16 = 18,432 B
    float* P = SM;                               // epilogue partials (32 KB, aliases X+Vs)

    int t = threadIdx.x;
    int lane = t & 63;
    int w = t >> 6;
    int sh = w >> 1;                             // ab half: a in {0..2} / {3..5}
    int cog = w & 1;                             // 16-cout group within block's 32
    int lo = lane & 15;                          // MFMA m/n: cout row (A) & tile (B)
    int kq = lane >> 4;                          // k-quad within MFMA

    // XCD swizzle: blockIdx round-robins XCDs; vid makes consecutive vids (incl.
    // cout-twins sharing a halo) land contiguously on one XCD -> halo L2 hit.
    int b = blockIdx.x;
    int vid = (b & 7) * 256 + (b >> 3);          // bijective, 2048 = 8*256
    int ch = vid & 1;                            // cout half (32 couts)
    int sb = (vid >> 1) & 63;
    int n = vid >> 7;

    int p0 = (sb >> 3) * 4;                      // super-block tile origin
    int q0 = (sb & 7) * 4;
    const float* xb = x + (size_t)n * 64 * 16384;
    int row0 = 4 * p0 - 1;
    int col0a = 4 * q0 - 4;                      // f4-aligned staging col origin

    int tl = t >> 4;                             // transform task: tile 0..15
    int ci = t & 15;                             // cin within quarter
    int tp = tl >> 2, tq = tl & 3;

    f32x4 acc[18];
#pragma unroll
    for (int i = 0; i < 18; i++) acc[i] = (f32x4){0.f, 0.f, 0.f, 0.f};

    for (int rq = 0; rq < 4; ++rq) {
        // ---- stage X: 16 cin x 18 rows x 6 f4-cols (1728 tasks, coalesced) ----
#pragma unroll
        for (int i = 0; i < 7; i++) {
            int s = i * 256 + t;
            if (s < 1728) {
                int cis = s / 108;               // 18*6
                int rs = s - cis * 108;
                int row = rs / 6;
                int c4 = rs - row * 6;
                int gr = row0 + row;
                int gc = col0a + 4 * c4;
                float v0 = 0.f, v1 = 0.f, v2 = 0.f, v3 = 0.f;
                if ((unsigned)gr < 128u) {
                    const float* rowp = xb + (size_t)((rq * 16 + cis) * 128 + gr) * 128;
                    if (gc >= 0 && gc + 3 < 128) {
                        f32x4 v = *(const f32x4*)(rowp + gc);
                        v0 = v[0]; v1 = v[1]; v2 = v[2]; v3 = v[3];
                    } else {
                        if ((unsigned)(gc + 0) < 128u) v0 = rowp[gc + 0];
                        if ((unsigned)(gc + 1) < 128u) v1 = rowp[gc + 1];
                        if ((unsigned)(gc + 2) < 128u) v2 = rowp[gc + 2];
                        if ((unsigned)(gc + 3) < 128u) v3 = rowp[gc + 3];
                    }
                }
                int base = cis * XS + row * 18;
                int cl = 4 * c4 - 3;             // local col of j=0
                if ((unsigned)(cl + 0) < 18u) X[base + cl + 0] = v0;
                if ((unsigned)(cl + 1) < 18u) X[base + cl + 1] = v1;
                if ((unsigned)(cl + 2) < 18u) X[base + cl + 2] = v2;
                if ((unsigned)(cl + 3) < 18u) X[base + cl + 3] = v3;
            }
        }
        __syncthreads();

        // ---- transform: 1 task/thread, all 36 ab -> Vs ----
        {
            const float* Xb = X + ci * XS + (4 * tp) * 18 + 4 * tq;
            _Float16* vb = Vs + tl * 16 + ci;
#pragma unroll
            for (int s2 = 0; s2 < 2; s2++) {     // a-rows 3*s2 .. 3*s2+2
                float Ua[3][6];
#pragma unroll
                for (int c = 0; c < 6; c++) {
                    float m0 = Xb[0 * 18 + c], m1 = Xb[1 * 18 + c], m2 = Xb[2 * 18 + c];
                    float m3 = Xb[3 * 18 + c], m4 = Xb[4 * 18 + c], m5 = Xb[5 * 18 + c];
                    if (s2 == 0) {
                        float e = fmaf(-4.f, m2, m4);
                        float f = fmaf(-4.f, m1, m3);
                        Ua[0][c] = fmaf(4.f, m0 - m2, m4 - m2);
                        Ua[1][c] = e + f;
                        Ua[2][c] = e - f;
                    } else {
                        float g = m4 - m2, h = m3 - m1;
                        Ua[0][c] = fmaf(2.f, h, g);
                        Ua[1][c] = fmaf(-2.f, h, g);
                        Ua[2][c] = fmaf(4.f, m1 - m3, m5 - m3);
                    }
                }
#pragma unroll
                for (int ar = 0; ar < 3; ar++) {
                    float m0 = Ua[ar][0], m1 = Ua[ar][1], m2 = Ua[ar][2];
                    float m3 = Ua[ar][3], m4 = Ua[ar][4], m5 = Ua[ar][5];
                    float e = fmaf(-4.f, m2, m4);
                    float f = fmaf(-4.f, m1, m3);
                    float g = m4 - m2;
                    float h = m3 - m1;
                    int abb = (s2 * 3 + ar) * 6;
                    vb[(abb + 0) * 256] = (_Float16)fmaf(4.f, m0 - m2, g);
                    vb[(abb + 1) * 256] = (_Float16)(e + f);
                    vb[(abb + 2) * 256] = (_Float16)(e - f);
                    vb[(abb + 3) * 256] = (_Float16)fmaf(2.f, h, g);
                    vb[(abb + 4) * 256] = (_Float16)fmaf(-2.f, h, g);
                    vb[(abb + 5) * 256] = (_Float16)fmaf(4.f, m1 - m3, m5 - m3);
                }
            }
        }
        __syncthreads();

        // ---- GEMM: 18 MFMAs (K=16); A from global wh (L2-hot), B from LDS ----
        {
            const _Float16* wbh = wh + (sh * 18) * 4096 + (size_t)(ch * 32 + cog * 16 + lo) * 64 + rq * 16 + kq * 4;
            const _Float16* vb2 = Vs + (sh * 18) * 256 + lo * 16 + kq * 4;
#pragma unroll
            for (int abl = 0; abl < 18; abl++) {
                f16x4 a = *(const f16x4*)(wbh + abl * 4096);
                f16x4 bf = *(const f16x4*)(vb2 + abl * 256);
                acc[abl] = __builtin_amdgcn_mfma_f32_16x16x16f16(a, bf, acc[abl], 0, 0, 0);
            }
        }
        // no barrier: next quarter's post-stage barrier guards Vs reuse
        // (stage only writes X, which transform already consumed)
    }

    // ---- epilogue: partial AT..AT^T per a-half, cross-wave combine via LDS ----
    // D layout: col=lo (tile), row=kq*4+rr (local cout); acc[ar*6+bb], a=3*sh+ar.
    __syncthreads();                             // MFMA done in all waves (P aliases Vs)
    int p = p0 + (lo >> 2);
    int q = q0 + (lo & 3);

    if (sh == 1) {                               // a=3,4,5 partial -> LDS
#pragma unroll
        for (int rr = 0; rr < 4; rr++) {
            float z[4][6];
#pragma unroll
            for (int bb = 0; bb < 6; bb++) {
                float m3 = acc[bb][rr], m4 = acc[6 + bb][rr], m5 = acc[12 + bb][rr];
                float sv = m3 + m4, dv = m3 - m4;
                z[0][bb] = sv;
                z[1][bb] = 2.f * dv;
                z[2][bb] = 4.f * sv;
                z[3][bb] = fmaf(8.f, dv, m5);
            }
#pragma unroll
            for (int xr = 0; xr < 4; xr++) {
                float s1 = z[xr][1] + z[xr][2], d1 = z[xr][1] - z[xr][2];
                float s2 = z[xr][3] + z[xr][4], d2 = z[xr][3] - z[xr][4];
                f32x4 y;
                y[0] = z[xr][0] + s1 + s2;
                y[1] = fmaf(2.f, d2, d1);
                y[2] = fmaf(4.f, s2, s1);
                y[3] = fmaf(8.f, d2, d1) + z[xr][5];
                // lane-linear: 64 lanes x 16B contiguous -> conflict-free b128
                *(f32x4*)&P[cog * 4096 + (rr * 4 + xr) * 256 + lane * 4] = y;
            }
        }
    }
    __syncthreads();
    if (sh == 0) {                               // a=0,1,2 partial + LDS partial + bias
#pragma unroll
        for (int rr = 0; rr < 4; rr++) {
            int co = ch * 32 + cog * 16 + kq * 4 + rr;
            float bv = bias[co];
            float z[4][6];
#pragma unroll
            for (int bb = 0; bb < 6; bb++) {
                float m0 = acc[bb][rr], m1 = acc[6 + bb][rr], m2 = acc[12 + bb][rr];
                float s1 = m1 + m2, d1 = m1 - m2;
                z[0][bb] = m0 + s1;
                z[1][bb] = d1;
                z[2][bb] = s1;
                z[3][bb] = d1;
            }
            float* ob = out + ((size_t)(n * 64 + co) * 128 + 4 * p) * 128 + 4 * q;
#pragma unroll
            for (int xr = 0; xr < 4; xr++) {
                float s1 = z[xr][1] + z[xr][2], d1 = z[xr][1] - z[xr][2];
                float s2 = z[xr][3] + z[xr][4], d2 = z[xr][3] - z[xr][4];
                f32x4 part = *(const f32x4*)&P[cog * 4096 + (rr * 4 + xr) * 256 + lane * 4];
                f32x4 y;
                y[0] = z[xr][0] + s1 + s2 + part[0] + bv;
                y[1] = fmaf(2.f, d2, d1) + part[1] + bv;
                y[2] = fmaf(4.f, s2, s1) + part[2] + bv;
                y[3] = fmaf(8.f, d2, d1) + z[xr][5] + part[3] + bv;
                *(f32x4*)(ob + xr * 128) = y;
            }
        }
    }
}

extern "C" void kernel_launch(void* const* d_in, const int* in_sizes, int n_in,
                              void* d_out, int out_size, void* d_ws, size_t ws_size,
                              hipStream_t stream) {
    const float* x    = (const float*)d_in[0];
    const float* wf   = (const float*)d_in[1];
    const float* bias = (const float*)d_in[2];
    float* out = (float*)d_out;

    if (ws_size < WB_BYTES) return;              // need 295 KB scratch for f16 weights
    _Float16* wh = (_Float16*)d_ws;

    wtrans<<<16, 256, 0, stream>>>(wf, wh);
    wino_fused<<<2048, 256, 0, stream>>>(x, wh, bias, out);
}

// Round 2
// 191.429 us; speedup vs baseline: 1.5180x; 1.5180x over previous
//
#include <hip/hip_runtime.h>
#include <stdint.h>

typedef __attribute__((ext_vector_type(4))) float f32x4;
typedef __attribute__((ext_vector_type(8))) short s16x8;

// ---- geometry (fixed problem) ----
// x: (16,64,128,128) fp32; weight: (64,64,6,6) fp32 (Winograd-domain); bias fp32
// out: (16,64,128,128) fp32. 4x4 output tiles, nt=32/dim, 16384 tiles, PAD=1.
#define WB_BYTES 294912              // 36*64*64 bf16 relayout of weights

__device__ __forceinline__ short f2bf(float f) {
    uint32_t u = __builtin_bit_cast(uint32_t, f);
    u = u + 0x7FFFu + ((u >> 16) & 1u);          // round-to-nearest-even
    return (short)(u >> 16);
}

// ---------------- Kernel 0: weight relayout fp32(co,cin,ab) -> bf16 [ab][co*64+cin] ----------------
__global__ __launch_bounds__(256) void wtrans(const float* __restrict__ wf, short* __restrict__ wb) {
    int tid = blockIdx.x * 256 + threadIdx.x;    // 0..4095  == co*64+cin
    const float* src = wf + tid * 36;
    float w[36];
#pragma unroll
    for (int i = 0; i < 9; i++) {
        f32x4 v = *(const f32x4*)(src + 4 * i);
        w[4*i+0] = v[0]; w[4*i+1] = v[1]; w[4*i+2] = v[2]; w[4*i+3] = v[3];
    }
#pragma unroll
    for (int ab = 0; ab < 36; ab++) wb[ab * 4096 + tid] = f2bf(w[ab]);  // coalesced per ab
}

// ---------------- Fused kernel ----------------
// Block = 4x4 tile super-block (16 tiles) x all 64 cout x all 64 cin. Grid 1024 (no
// duplicated halo work). 512 threads = 8 waves = (cog: 4 x 16-cout) x (sh: ab half).
// Per cin half r (32 cin): stage 18x18x32 halo into X; transform 512 (tile,cin)
// tasks (1/thread) -> Vs [36ab][tile16][cin32] bf16; each wave runs 18 K=32 MFMAs
// for its 18 ab into acc[18] (AGPR<=128, arch VGPR ~80 -> 4 waves/SIMD, no spills;
// launch_bounds min-waves kept at 2 so the compiler is NOT register-starved —
// forcing 4 in round 1 caused ~130 MB of scratch spill traffic).
// LDS 80.8 KB -> exactly 2 blocks/CU = 16 waves/CU.
// Epilogue: sh=1 partial AT rows -> LDS P (aliases X/Vs), sh=0 combines+bias+stores.
#define XS 343                                   // 18*18=324 padded to odd 343
__global__ __launch_bounds__(512, 2) void wino_fused(const float* __restrict__ x,
                                                     const short* __restrict__ wb,
                                                     const float* __restrict__ bias,
                                                     float* __restrict__ out) {
    __shared__ __align__(16) float SM[20192];    // 80,768 B -> 2 blocks/CU
    float* X = SM;                               // [32][343] fp32 = 43,904 B
    short* Vs = (short*)(SM + 32 * XS);          // [36][16][32] bf16 = 36,864 B
    float* P = SM;                               // epilogue partials 64 KB (aliases X+Vs)

    int t = threadIdx.x;
    int lane = t & 63;
    int w = t >> 6;                              // 0..7
    int cog = w >> 1;                            // 0..3 : 16-cout group
    int sh = w & 1;                              // ab half: a in {0..2} / {3..5}
    int lo = lane & 15;                          // MFMA m/n: cout row (A) & tile (B)
    int kq = lane >> 4;                          // k-quad within MFMA

    int b = blockIdx.x;
    int n = b >> 6;
    int sb = b & 63;
    int p0 = (sb >> 3) * 4;                      // super-block tile origin
    int q0 = (sb & 7) * 4;
    const float* xb = x + (size_t)n * 64 * 16384;
    int row0 = 4 * p0 - 1;
    int col0a = 4 * q0 - 4;                      // f4-aligned staging col origin

    int tl = t >> 5;                             // transform task: tile 0..15
    int ci = t & 31;                             // cin within half
    int tp = tl >> 2, tq = tl & 3;

    f32x4 acc[18];
#pragma unroll
    for (int i = 0; i < 18; i++) acc[i] = (f32x4){0.f, 0.f, 0.f, 0.f};

#pragma unroll
    for (int r = 0; r < 2; r++) {
        // ---- stage X: 32 cin x 18 rows x 6 f4-cols (3456 tasks over 512 thr) ----
#pragma unroll
        for (int i = 0; i < 7; i++) {
            int s = i * 512 + t;
            if (s < 3456) {
                int cis = s / 108;               // 18*6
                int rs = s - cis * 108;
                int row = rs / 6;
                int c4 = rs - row * 6;
                int gr = row0 + row;
                int gc = col0a + 4 * c4;
                float v0 = 0.f, v1 = 0.f, v2 = 0.f, v3 = 0.f;
                if ((unsigned)gr < 128u) {
                    const float* rowp = xb + (size_t)((r * 32 + cis) * 128 + gr) * 128;
                    if (gc >= 0 && gc + 3 < 128) {
                        f32x4 v = *(const f32x4*)(rowp + gc);
                        v0 = v[0]; v1 = v[1]; v2 = v[2]; v3 = v[3];
                    } else {
                        if ((unsigned)(gc + 0) < 128u) v0 = rowp[gc + 0];
                        if ((unsigned)(gc + 1) < 128u) v1 = rowp[gc + 1];
                        if ((unsigned)(gc + 2) < 128u) v2 = rowp[gc + 2];
                        if ((unsigned)(gc + 3) < 128u) v3 = rowp[gc + 3];
                    }
                }
                int base = cis * XS + row * 18;
                int cl = 4 * c4 - 3;             // local col of j=0
                if ((unsigned)(cl + 0) < 18u) X[base + cl + 0] = v0;
                if ((unsigned)(cl + 1) < 18u) X[base + cl + 1] = v1;
                if ((unsigned)(cl + 2) < 18u) X[base + cl + 2] = v2;
                if ((unsigned)(cl + 3) < 18u) X[base + cl + 3] = v3;
            }
        }
        __syncthreads();

        // ---- transform: 1 task/thread, all 36 ab -> Vs ----
        {
            const float* Xb = X + ci * XS + (4 * tp) * 18 + 4 * tq;
            short* vb = Vs + tl * 32 + ci;
#pragma unroll
            for (int s2 = 0; s2 < 2; s2++) {     // a-rows 3*s2 .. 3*s2+2
                float Ua[3][6];
#pragma unroll
                for (int c = 0; c < 6; c++) {
                    float m0 = Xb[0 * 18 + c], m1 = Xb[1 * 18 + c], m2 = Xb[2 * 18 + c];
                    float m3 = Xb[3 * 18 + c], m4 = Xb[4 * 18 + c], m5 = Xb[5 * 18 + c];
                    if (s2 == 0) {
                        float e = fmaf(-4.f, m2, m4);
                        float f = fmaf(-4.f, m1, m3);
                        Ua[0][c] = fmaf(4.f, m0 - m2, m4 - m2);
                        Ua[1][c] = e + f;
                        Ua[2][c] = e - f;
                    } else {
                        float g = m4 - m2, h = m3 - m1;
                        Ua[0][c] = fmaf(2.f, h, g);
                        Ua[1][c] = fmaf(-2.f, h, g);
                        Ua[2][c] = fmaf(4.f, m1 - m3, m5 - m3);
                    }
                }
#pragma unroll
                for (int ar = 0; ar < 3; ar++) {
                    float m0 = Ua[ar][0], m1 = Ua[ar][1], m2 = Ua[ar][2];
                    float m3 = Ua[ar][3], m4 = Ua[ar][4], m5 = Ua[ar][5];
                    float e = fmaf(-4.f, m2, m4);
                    float f = fmaf(-4.f, m1, m3);
                    float g = m4 - m2;
                    float h = m3 - m1;
                    int abb = (s2 * 3 + ar) * 6;
                    vb[(abb + 0) * 512] = f2bf(fmaf(4.f, m0 - m2, g));
                    vb[(abb + 1) * 512] = f2bf(e + f);
                    vb[(abb + 2) * 512] = f2bf(e - f);
                    vb[(abb + 3) * 512] = f2bf(fmaf(2.f, h, g));
                    vb[(abb + 4) * 512] = f2bf(fmaf(-2.f, h, g));
                    vb[(abb + 5) * 512] = f2bf(fmaf(4.f, m1 - m3, m5 - m3));
                }
            }
        }
        __syncthreads();

        // ---- GEMM: 18 MFMAs (K=32) per wave for its 18 ab; A from L2-hot wb ----
        {
            const short* wb_base = wb + (sh * 18) * 4096 + (cog * 16 + lo) * 64 + r * 32 + kq * 8;
            const short* v_base = Vs + (sh * 18) * 512 + lo * 32 + kq * 8;
#pragma unroll
            for (int abl = 0; abl < 18; abl++) {
                s16x8 a0 = *(const s16x8*)(wb_base + abl * 4096);
                s16x8 b0 = *(const s16x8*)(v_base + abl * 512);
                acc[abl] = __builtin_amdgcn_mfma_f32_16x16x32_bf16(a0, b0, acc[abl], 0, 0, 0);
            }
        }
        // no barrier here: next r's post-stage barrier orders gemm(Vs reads) vs
        // next transform(Vs writes); stage itself only touches X (disjoint).
    }

    // ---- epilogue: partial AT..AT^T per a-half, cross-wave combine via LDS ----
    // D layout: col=lo (tile), row=kq*4+rr (local cout); acc[ar*6+bb], a=3*sh+ar.
    __syncthreads();                             // all gemm done (P aliases Vs/X)
    int p = p0 + (lo >> 2);
    int q = q0 + (lo & 3);

    if (sh == 1) {                               // a=3,4,5 partial -> LDS
#pragma unroll
        for (int rr = 0; rr < 4; rr++) {
            float z[4][6];
#pragma unroll
            for (int bb = 0; bb < 6; bb++) {
                float m3 = acc[bb][rr], m4 = acc[6 + bb][rr], m5 = acc[12 + bb][rr];
                float sv = m3 + m4, dv = m3 - m4;
                z[0][bb] = sv;
                z[1][bb] = 2.f * dv;
                z[2][bb] = 4.f * sv;
                z[3][bb] = fmaf(8.f, dv, m5);
            }
#pragma unroll
            for (int xr = 0; xr < 4; xr++) {
                float s1 = z[xr][1] + z[xr][2], d1 = z[xr][1] - z[xr][2];
                float s2 = z[xr][3] + z[xr][4], d2 = z[xr][3] - z[xr][4];
                f32x4 y;
                y[0] = z[xr][0] + s1 + s2;
                y[1] = fmaf(2.f, d2, d1);
                y[2] = fmaf(4.f, s2, s1);
                y[3] = fmaf(8.f, d2, d1) + z[xr][5];
                // lane-linear: 64 lanes x 16B contiguous -> conflict-free b128
                *(f32x4*)&P[cog * 4096 + (rr * 4 + xr) * 256 + lane * 4] = y;
            }
        }
    }
    __syncthreads();
    if (sh == 0) {                               // a=0,1,2 partial + LDS partial + bias
#pragma unroll
        for (int rr = 0; rr < 4; rr++) {
            int co = cog * 16 + kq * 4 + rr;
            float bv = bias[co];
            float z[4][6];
#pragma unroll
            for (int bb = 0; bb < 6; bb++) {
                float m0 = acc[bb][rr], m1 = acc[6 + bb][rr], m2 = acc[12 + bb][rr];
                float s1 = m1 + m2, d1 = m1 - m2;
                z[0][bb] = m0 + s1;
                z[1][bb] = d1;
                z[2][bb] = s1;
                z[3][bb] = d1;
            }
            float* ob = out + ((size_t)(n * 64 + co) * 128 + 4 * p) * 128 + 4 * q;
#pragma unroll
            for (int xr = 0; xr < 4; xr++) {
                float s1 = z[xr][1] + z[xr][2], d1 = z[xr][1] - z[xr][2];
                float s2 = z[xr][3] + z[xr][4], d2 = z[xr][3] - z[xr][4];
                f32x4 part = *(const f32x4*)&P[cog * 4096 + (rr * 4 + xr) * 256 + lane * 4];
                f32x4 y;
                y[0] = z[xr][0] + s1 + s2 + part[0] + bv;
                y[1] = fmaf(2.f, d2, d1) + part[1] + bv;
                y[2] = fmaf(4.f, s2, s1) + part[2] + bv;
                y[3] = fmaf(8.f, d2, d1) + z[xr][5] + part[3] + bv;
                *(f32x4*)(ob + xr * 128) = y;
            }
        }
    }
}

extern "C" void kernel_launch(void* const* d_in, const int* in_sizes, int n_in,
                              void* d_out, int out_size, void* d_ws, size_t ws_size,
                              hipStream_t stream) {
    const float* x    = (const float*)d_in[0];
    const float* wf   = (const float*)d_in[1];
    const float* bias = (const float*)d_in[2];
    float* out = (float*)d_out;

    if (ws_size < WB_BYTES) return;              // need 295 KB scratch for bf16 weights
    short* wb = (short*)d_ws;

    wtrans<<<16, 256, 0, stream>>>(wf, wb);
    wino_fused<<<1024, 512, 0, stream>>>(x, wb, bias, out);
}

// Round 3
// 185.855 us; speedup vs baseline: 1.5636x; 1.0300x over previous
//
#include <hip/hip_runtime.h>
#include <stdint.h>

typedef __attribute__((ext_vector_type(4))) float f32x4;
typedef __attribute__((ext_vector_type(8))) short s16x8;

// ---- geometry (fixed problem) ----
// x: (16,64,128,128) fp32; weight: (64,64,6,6) fp32 (Winograd-domain); bias fp32
// out: (16,64,128,128) fp32. 4x4 output tiles, nt=32/dim, 16384 tiles, PAD=1.
#define WB_BYTES 294912              // 36*64*64 bf16 relayout of weights

__device__ __forceinline__ short f2bf(float f) {
    uint32_t u = __builtin_bit_cast(uint32_t, f);
    u = u + 0x7FFFu + ((u >> 16) & 1u);          // round-to-nearest-even
    return (short)(u >> 16);
}

// ---------------- Kernel 0: weight relayout fp32(co,cin,ab) -> bf16 [ab][co*64+cin] ----------------
__global__ __launch_bounds__(256) void wtrans(const float* __restrict__ wf, short* __restrict__ wb) {
    int tid = blockIdx.x * 256 + threadIdx.x;    // 0..4095  == co*64+cin
    const float* src = wf + tid * 36;
    float w[36];
#pragma unroll
    for (int i = 0; i < 9; i++) {
        f32x4 v = *(const f32x4*)(src + 4 * i);
        w[4*i+0] = v[0]; w[4*i+1] = v[1]; w[4*i+2] = v[2]; w[4*i+3] = v[3];
    }
#pragma unroll
    for (int ab = 0; ab < 36; ab++) wb[ab * 4096 + tid] = f2bf(w[ab]);  // coalesced per ab
}

// ---------------- Fused kernel ----------------
// OCCUPANCY MODEL (measured R0/R2): CU unified VGPR+AGPR pool = 2048 regs/wave-slots;
// resident waves = min(floor(2048/(arch+acc)), LDS blocks) at BLOCK granularity.
// R2: (68+72)=140 -> 14 waves, but 512t block needs 16 atomically -> 1 block = 8 waves.
// Fix: ONE 1024-thread block (16 waves) owns the whole super-block; acc shrinks to
// acc[9]=36 AGPR/wave; (arch~75+36)*16 ~ 1780 <= 2048 -> 16 waves/CU resident (50%).
// 16 waves = 4 cog (16-cout groups) x (sh: a-half) x (bh: b-half); each wave does a
// 3x3 ab-subtile (9 MFMAs K=32 per cin-half). Epilogue: AT..AT^T is linear in a and b
// -> 4 partial 4x4 y's per cog, combined via two 64KB LDS buffers in 3 phases, final
// store parallel across all 16 waves (one output row-group rr each).
#define XS 343                                   // 18*18=324 padded to odd 343 (bank-perm)
__global__ __launch_bounds__(1024) void wino_fused(const float* __restrict__ x,
                                                   const short* __restrict__ wb,
                                                   const float* __restrict__ bias,
                                                   float* __restrict__ out) {
    __shared__ __align__(16) float SM[32768];    // 128 KiB (1 block/CU anyway — regs cap it)
    float* X = SM;                               // [32][343] fp32 = 43,904 B
    short* Vs = (short*)(SM + 32 * XS);          // [36][16][32] bf16 = 36,864 B
    float* P0 = SM;                              // epilogue partials sh=0 pair (64 KB)
    float* P1 = SM + 16384;                      // epilogue partials sh=1 pair (64 KB)

    int t = threadIdx.x;
    int lane = t & 63;
    int w = t >> 6;                              // 0..15
    int cog = w >> 2;                            // 0..3 : 16-cout group
    int grp = w & 3;                             // (sh,bh)
    int sh = grp >> 1;                           // a-half: a in {0..2} / {3..5}
    int bh = grp & 1;                            // b-half: b in {0..2} / {3..5}
    int lo = lane & 15;                          // MFMA m/n: cout row (A) & tile (B)
    int kq = lane >> 4;                          // k-quad within MFMA

    int b = blockIdx.x;
    int n = b >> 6;
    int sb = b & 63;
    int p0_ = (sb >> 3) * 4;                     // super-block tile origin
    int q0_ = (sb & 7) * 4;
    const float* xb = x + (size_t)n * 64 * 16384;
    int row0 = 4 * p0_ - 1;
    int col0a = 4 * q0_ - 4;                     // f4-aligned staging col origin

    // transform task: exactly 1 per thread: (s2-half, tile, cin)
    int ci_t = t & 31;                           // cin within half
    int tl_t = (t >> 5) & 15;                    // tile 0..15
    int s2_t = t >> 9;                           // a-rows 0-2 / 3-5 (uniform per wave)
    int tp = tl_t >> 2, tq = tl_t & 3;

    f32x4 acc[9];
#pragma unroll
    for (int i = 0; i < 9; i++) acc[i] = (f32x4){0.f, 0.f, 0.f, 0.f};

#pragma unroll
    for (int r = 0; r < 2; r++) {
        // ---- stage X: 32 cin x 18 rows x 6 f4-cols (3456 tasks over 1024 thr) ----
#pragma unroll
        for (int i = 0; i < 4; i++) {
            int s = i * 1024 + t;
            if (s < 3456) {
                int cis = s / 108;               // 18*6
                int rs = s - cis * 108;
                int row = rs / 6;
                int c4 = rs - row * 6;
                int gr = row0 + row;
                int gc = col0a + 4 * c4;
                float v0 = 0.f, v1 = 0.f, v2 = 0.f, v3 = 0.f;
                if ((unsigned)gr < 128u) {
                    const float* rowp = xb + (size_t)((r * 32 + cis) * 128 + gr) * 128;
                    if (gc >= 0 && gc + 3 < 128) {
                        f32x4 v = *(const f32x4*)(rowp + gc);
                        v0 = v[0]; v1 = v[1]; v2 = v[2]; v3 = v[3];
                    } else {
                        if ((unsigned)(gc + 0) < 128u) v0 = rowp[gc + 0];
                        if ((unsigned)(gc + 1) < 128u) v1 = rowp[gc + 1];
                        if ((unsigned)(gc + 2) < 128u) v2 = rowp[gc + 2];
                        if ((unsigned)(gc + 3) < 128u) v3 = rowp[gc + 3];
                    }
                }
                int base = cis * XS + row * 18;
                int cl = 4 * c4 - 3;             // local col of j=0
                if ((unsigned)(cl + 0) < 18u) X[base + cl + 0] = v0;
                if ((unsigned)(cl + 1) < 18u) X[base + cl + 1] = v1;
                if ((unsigned)(cl + 2) < 18u) X[base + cl + 2] = v2;
                if ((unsigned)(cl + 3) < 18u) X[base + cl + 3] = v3;
            }
        }
        __syncthreads();

        // ---- transform: 1 task/thread (tile, cin, 3 a-rows) -> Vs ----
        {
            const float* Xb = X + ci_t * XS + (4 * tp) * 18 + 4 * tq;
            float Ua[3][6];
#pragma unroll
            for (int c = 0; c < 6; c++) {
                if (s2_t == 0) {
                    float m0 = Xb[0 * 18 + c], m1 = Xb[1 * 18 + c], m2 = Xb[2 * 18 + c];
                    float m3 = Xb[3 * 18 + c], m4 = Xb[4 * 18 + c];
                    float e = fmaf(-4.f, m2, m4);
                    float f = fmaf(-4.f, m1, m3);
                    Ua[0][c] = fmaf(4.f, m0 - m2, m4 - m2);
                    Ua[1][c] = e + f;
                    Ua[2][c] = e - f;
                } else {
                    float m1 = Xb[1 * 18 + c], m2 = Xb[2 * 18 + c];
                    float m3 = Xb[3 * 18 + c], m4 = Xb[4 * 18 + c], m5 = Xb[5 * 18 + c];
                    float g = m4 - m2, h = m3 - m1;
                    Ua[0][c] = fmaf(2.f, h, g);
                    Ua[1][c] = fmaf(-2.f, h, g);
                    Ua[2][c] = fmaf(4.f, m1 - m3, m5 - m3);
                }
            }
            short* vb = Vs + tl_t * 32 + ci_t;
#pragma unroll
            for (int ar = 0; ar < 3; ar++) {
                float m0 = Ua[ar][0], m1 = Ua[ar][1], m2 = Ua[ar][2];
                float m3 = Ua[ar][3], m4 = Ua[ar][4], m5 = Ua[ar][5];
                float e = fmaf(-4.f, m2, m4);
                float f = fmaf(-4.f, m1, m3);
                float g = m4 - m2;
                float h = m3 - m1;
                int abb = (s2_t * 3 + ar) * 6;
                vb[(abb + 0) * 512] = f2bf(fmaf(4.f, m0 - m2, g));
                vb[(abb + 1) * 512] = f2bf(e + f);
                vb[(abb + 2) * 512] = f2bf(e - f);
                vb[(abb + 3) * 512] = f2bf(fmaf(2.f, h, g));
                vb[(abb + 4) * 512] = f2bf(fmaf(-2.f, h, g));
                vb[(abb + 5) * 512] = f2bf(fmaf(4.f, m1 - m3, m5 - m3));
            }
        }
        __syncthreads();

        // ---- GEMM: 9 MFMAs (K=32) on this wave's 3x3 ab-subtile; A from L2-hot wb ----
        {
            const short* wb_base = wb + (cog * 16 + lo) * 64 + r * 32 + kq * 8;
            const short* v_base = Vs + lo * 32 + kq * 8;
#pragma unroll
            for (int ar = 0; ar < 3; ar++) {
#pragma unroll
                for (int br = 0; br < 3; br++) {
                    int ab = (3 * sh + ar) * 6 + (3 * bh + br);
                    s16x8 a0 = *(const s16x8*)(wb_base + ab * 4096);
                    s16x8 b0 = *(const s16x8*)(v_base + ab * 512);
                    acc[ar * 3 + br] = __builtin_amdgcn_mfma_f32_16x16x32_bf16(a0, b0, acc[ar * 3 + br], 0, 0, 0);
                }
            }
        }
        // no trailing barrier: next r's post-stage barrier orders gemm(Vs reads) vs
        // next transform(Vs writes); stage itself only touches X (already consumed).
    }

    // ---- epilogue: 4-way partial AT..AT^T, combine via P0/P1, parallel store ----
    // D layout: col=lo (tile), row=kq*4+rr (cout in cog); acc[ar*3+br], a=3sh+ar, b=3bh+br.
    __syncthreads();                             // all gemm done (P aliases X/Vs)
    int p = p0_ + (lo >> 2);
    int q = q0_ + (lo & 3);
    float* Pown = (sh == 0) ? P0 : P1;

    // phase 1: bh=0 waves write their partial into P(sh)
    if (bh == 0) {
#pragma unroll
        for (int rr = 0; rr < 4; rr++) {
            float z[4][3];
#pragma unroll
            for (int br = 0; br < 3; br++) {
                float ma = acc[br][rr], mb = acc[3 + br][rr], mc = acc[6 + br][rr];
                if (sh == 0) {                   // a=0,1,2
                    float s1 = mb + mc, d1 = mb - mc;
                    z[0][br] = ma + s1; z[1][br] = d1; z[2][br] = s1; z[3][br] = d1;
                } else {                         // a=3,4,5
                    float sv = ma + mb, dv = ma - mb;
                    z[0][br] = sv; z[1][br] = 2.f * dv; z[2][br] = 4.f * sv;
                    z[3][br] = fmaf(8.f, dv, mc);
                }
            }
#pragma unroll
            for (int xr = 0; xr < 4; xr++) {     // b=0,1,2 partial
                float s1 = z[xr][1] + z[xr][2], d1 = z[xr][1] - z[xr][2];
                f32x4 y;
                y[0] = z[xr][0] + s1; y[1] = d1; y[2] = s1; y[3] = d1;
                *(f32x4*)&Pown[cog * 4096 + (rr * 4 + xr) * 256 + lane * 4] = y;
            }
        }
    }
    __syncthreads();
    // phase 2: bh=1 waves add their partial into P(sh)
    if (bh == 1) {
#pragma unroll
        for (int rr = 0; rr < 4; rr++) {
            float z[4][3];
#pragma unroll
            for (int br = 0; br < 3; br++) {
                float ma = acc[br][rr], mb = acc[3 + br][rr], mc = acc[6 + br][rr];
                if (sh == 0) {
                    float s1 = mb + mc, d1 = mb - mc;
                    z[0][br] = ma + s1; z[1][br] = d1; z[2][br] = s1; z[3][br] = d1;
                } else {
                    float sv = ma + mb, dv = ma - mb;
                    z[0][br] = sv; z[1][br] = 2.f * dv; z[2][br] = 4.f * sv;
                    z[3][br] = fmaf(8.f, dv, mc);
                }
            }
#pragma unroll
            for (int xr = 0; xr < 4; xr++) {     // b=3,4,5 partial
                float s2 = z[xr][0] + z[xr][1], d2 = z[xr][0] - z[xr][1];
                f32x4 y;
                y[0] = s2; y[1] = 2.f * d2; y[2] = 4.f * s2;
                y[3] = fmaf(8.f, d2, z[xr][2]);
                float* pp = &Pown[cog * 4096 + (rr * 4 + xr) * 256 + lane * 4];
                f32x4 old = *(const f32x4*)pp;
                *(f32x4*)pp = old + y;
            }
        }
    }
    __syncthreads();
    // phase 3: all 16 waves store; wave (cog,grp) handles rr=grp
    {
        int rr = grp;
        int co = cog * 16 + kq * 4 + rr;
        float bv = bias[co];
        float* ob = out + ((size_t)(n * 64 + co) * 128 + 4 * p) * 128 + 4 * q;
#pragma unroll
        for (int xr = 0; xr < 4; xr++) {
            int idx = cog * 4096 + (rr * 4 + xr) * 256 + lane * 4;
            f32x4 a0 = *(const f32x4*)&P0[idx];
            f32x4 a1 = *(const f32x4*)&P1[idx];
            f32x4 y;
            y[0] = a0[0] + a1[0] + bv;
            y[1] = a0[1] + a1[1] + bv;
            y[2] = a0[2] + a1[2] + bv;
            y[3] = a0[3] + a1[3] + bv;
            *(f32x4*)(ob + xr * 128) = y;
        }
    }
}

extern "C" void kernel_launch(void* const* d_in, const int* in_sizes, int n_in,
                              void* d_out, int out_size, void* d_ws, size_t ws_size,
                              hipStream_t stream) {
    const float* x    = (const float*)d_in[0];
    const float* wf   = (const float*)d_in[1];
    const float* bias = (const float*)d_in[2];
    float* out = (float*)d_out;

    if (ws_size < WB_BYTES) return;              // need 295 KB scratch for bf16 weights
    short* wb = (short*)d_ws;

    wtrans<<<16, 256, 0, stream>>>(wf, wb);
    wino_fused<<<1024, 1024, 0, stream>>>(x, wb, bias, out);
}